// Round 2
// baseline (4539.000 us; speedup 1.0000x reference)
//
#include <hip/hip_runtime.h>
#include <hip/hip_bf16.h>

#define N_NODES   50000
#define N_REL     16
#define HID       128
#define N_EDGES   1600000
#define N_TILES   3125          // N_NODES/16
#define N_BINS    800000        // N_TILES*256
#define KTOT      2176          // 17*128 (16 relations + root)
#define N_SCANBLK 782           // ceil(N_BINS/1024)

typedef unsigned short ushort_t;
typedef __attribute__((ext_vector_type(8))) short short8;
typedef __attribute__((ext_vector_type(4))) float f32x4;

union BF2U { __hip_bfloat162 h; unsigned u; };

__device__ __forceinline__ unsigned pack_bf16_2(float x, float y) {
  BF2U c; c.h = __float22bfloat162_rn(make_float2(x, y));
  return c.u;
}

// ---------------- setup kernels ----------------

__global__ __launch_bounds__(256) void k_zero(int* p, int n) {
  int i = blockIdx.x * 256 + threadIdx.x;
  if (i < n) p[i] = 0;
}

__global__ __launch_bounds__(256) void k_hist(const int* __restrict__ ei,
                                              const int* __restrict__ et,
                                              int* __restrict__ hist) {
  int e = blockIdx.x * 256 + threadIdx.x;   // grid covers E exactly
  int tgt = ei[N_EDGES + e];
  int r   = et[e];
  int key = ((tgt >> 4) << 8) | (r << 4) | (tgt & 15);
  atomicAdd(&hist[key], 1);
}

__global__ __launch_bounds__(256) void k_btot(const int* __restrict__ hist,
                                              int* __restrict__ totals) {
  __shared__ int s[256];
  int t = threadIdx.x, b = blockIdx.x;
  int sum = 0;
  for (int j = 0; j < 4; ++j) {
    int idx = b * 1024 + j * 256 + t;
    sum += (idx < N_BINS) ? hist[idx] : 0;
  }
  s[t] = sum; __syncthreads();
  for (int ofs = 128; ofs > 0; ofs >>= 1) {
    if (t < ofs) s[t] += s[t + ofs];
    __syncthreads();
  }
  if (t == 0) totals[b] = s[0];
}

__global__ __launch_bounds__(1024) void k_scan_totals(int* totals, int* off) {
  __shared__ int s[1024];
  int t = threadIdx.x;
  int v = (t < N_SCANBLK) ? totals[t] : 0;
  s[t] = v; __syncthreads();
  for (int ofs = 1; ofs < 1024; ofs <<= 1) {
    int x = (t >= ofs) ? s[t - ofs] : 0;
    __syncthreads();
    s[t] += x;
    __syncthreads();
  }
  if (t < N_SCANBLK) totals[t] = s[t] - v;   // exclusive scan of block totals
  if (t == 0) off[N_BINS] = N_EDGES;
}

__global__ __launch_bounds__(1024) void k_scan_within(int* __restrict__ hist /* becomes off in place */,
                                                      const int* __restrict__ totals,
                                                      int* __restrict__ cursors) {
  __shared__ int s[1024];
  int t = threadIdx.x, blk = blockIdx.x;
  int b = blk * 1024 + t;
  int v = (b < N_BINS) ? hist[b] : 0;
  s[t] = v; __syncthreads();
  for (int ofs = 1; ofs < 1024; ofs <<= 1) {
    int x = (t >= ofs) ? s[t - ofs] : 0;
    __syncthreads();
    s[t] += x;
    __syncthreads();
  }
  if (b < N_BINS) {
    int e = totals[blk] + s[t] - v;
    hist[b] = e;        // exclusive global offset
    cursors[b] = e;
  }
}

__global__ __launch_bounds__(256) void k_sort(const int* __restrict__ ei,
                                              const int* __restrict__ et,
                                              int* __restrict__ cursors,
                                              int* __restrict__ payload) {
  int e = blockIdx.x * 256 + threadIdx.x;
  int src = ei[e];
  int tgt = ei[N_EDGES + e];
  int r   = et[e];
  int key = ((tgt >> 4) << 8) | (r << 4) | (tgt & 15);
  int pos = atomicAdd(&cursors[key], 1);
  payload[pos] = (src << 4) | (tgt & 15);
}

// Bt[l][o][k] = bf16 of (k<2048 ? W[l][k>>7][k&127][o] : root[l][k-2048][o])
__global__ __launch_bounds__(256) void k_bt(const float* __restrict__ W,
                                            const float* __restrict__ root,
                                            ushort_t* __restrict__ Bt) {
  int idx = blockIdx.x * 256 + threadIdx.x;    // 3*128*2176 exact
  int l   = idx / (HID * KTOT);
  int rem = idx - l * HID * KTOT;
  int o   = rem / KTOT;
  int k   = rem - o * KTOT;
  float v;
  if (k < 2048) {
    int r = k >> 7, d = k & 127;
    v = W[((l * N_REL + r) * HID + d) * HID + o];
  } else {
    int d = k - 2048;
    v = root[(l * HID + d) * HID + o];
  }
  __hip_bfloat16 h = __float2bfloat16(v);
  union { __hip_bfloat16 h; ushort_t u; } c; c.h = h;
  Bt[idx] = c.u;
}

// xh = bf16(x)  (layer-0 input conversion only; relu fused in k_main epilogue)
__global__ __launch_bounds__(256) void k_xh(const float* __restrict__ xin,
                                            ushort_t* __restrict__ xh) {
  int i = blockIdx.x * 256 + threadIdx.x;      // grid = N*H/4 exact
  float4 v = ((const float4*)xin)[i];
  uint2 u;
  u.x = pack_bf16_2(v.x, v.y);
  u.y = pack_bf16_2(v.z, v.w);
  ((uint2*)xh)[i] = u;
}

// ---------------- fused per-layer kernel ----------------
// Block: 16-node tile, 4 waves. Each wave owns 32 output cols (2 C-frags).
// 4 relation-groups: wave w gathers relation g*4+w into its own LDS agg
// block; gather is pipelined 16-deep with payload pre-broadcast via shfl.
// Root (x @ root) is a 17th K-block read directly from global xh.
// Epilogue: layers 0,1 -> bf16(relu(acc+bias)) into xh_out; layer 2 -> f32 out.

__global__ __launch_bounds__(256) void k_main(const ushort_t* __restrict__ xh,
                                              ushort_t* __restrict__ xh_out,
                                              float* __restrict__ fout,
                                              const ushort_t* __restrict__ Bt,
                                              const float* __restrict__ bias,
                                              const int* __restrict__ off,
                                              const int* __restrict__ payload,
                                              int write_f32) {
  __shared__ float agg[4][16][132];   // +4 f32 pad: A-frag reads cheap-conflicted
  __shared__ float scl[64];

  const int tile = blockIdx.x;
  const int tid  = threadIdx.x;
  const int wave = tid >> 6;
  const int lane = tid & 63;
  const int m16  = lane & 15;
  const int q    = lane >> 4;

  f32x4 acc0 = {0.f, 0.f, 0.f, 0.f};
  f32x4 acc1 = {0.f, 0.f, 0.f, 0.f};

  const unsigned* xh32 = (const unsigned*)xh;

  for (int g = 0; g < 4; ++g) {
    // zero this wave's agg block (128 cols; pad never read)
    {
      float4 z = {0.f, 0.f, 0.f, 0.f};
      for (int i = lane; i < 512; i += 64) {
        int m = i >> 5, c = (i & 31) << 2;
        *(float4*)&agg[wave][m][c] = z;
      }
    }
    if (tid < 64) {
      int rl = tid >> 4, m = tid & 15;
      int bin = tile * 256 + (g * 4 + rl) * 16 + m;
      int c = off[bin + 1] - off[bin];
      scl[tid] = (c > 0) ? (1.0f / (float)c) : 0.f;
    }
    __syncthreads();

    // -------- gather: wave handles relation g*4+wave (contiguous edge run) ----
    // Payloads for a 64-edge chunk come from ONE coalesced load + shfl
    // broadcast (no per-edge payload latency). xh gathers issue 16-deep.
    {
      int base = tile * 256 + (g * 4 + wave) * 16;
      int e0 = off[base];
      int e1 = off[base + 16];
      for (int c0 = e0; c0 < e1; c0 += 64) {
        int rem = e1 - c0;
        int nb  = rem < 64 ? rem : 64;
        int pv  = payload[c0 + (lane < nb ? lane : nb - 1)];
        for (int j = 0; j < nb; j += 16) {
          int p[16]; unsigned x[16]; float s[16];
#pragma unroll
          for (int k = 0; k < 16; ++k) {
            int idx = j + k;
            p[k] = __shfl(pv, idx < nb ? idx : nb - 1);
          }
#pragma unroll
          for (int k = 0; k < 16; ++k)
            x[k] = xh32[(p[k] >> 4) * 64 + lane];
#pragma unroll
          for (int k = 0; k < 16; ++k)
            s[k] = (j + k < nb) ? scl[wave * 16 + (p[k] & 15)] : 0.f;
#pragma unroll
          for (int k = 0; k < 16; ++k) {
            float lo = __uint_as_float(x[k] << 16);
            float hi = __uint_as_float(x[k] & 0xffff0000u);
            int   m  = p[k] & 15;
            atomicAdd(&agg[wave][m][lane * 2],     lo * s[k]);
            atomicAdd(&agg[wave][m][lane * 2 + 1], hi * s[k]);
          }
        }
      }
    }
    __syncthreads();

    // -------- MFMA this group's K = 4*128 --------
    const int colA = wave * 32 + m16;
#pragma unroll
    for (int kk = 0; kk < 16; ++kk) {
      int rl = kk >> 2;
      int ko = (kk & 3) * 32 + q * 8;
      const float* ap = &agg[rl][m16][ko];
      float4 a0 = *(const float4*)ap;
      float4 a1 = *(const float4*)(ap + 4);
      union { unsigned u[4]; short8 s; } av;
      av.u[0] = pack_bf16_2(a0.x, a0.y);
      av.u[1] = pack_bf16_2(a0.z, a0.w);
      av.u[2] = pack_bf16_2(a1.x, a1.y);
      av.u[3] = pack_bf16_2(a1.z, a1.w);
      int kglob = g * 512 + kk * 32 + q * 8;
      const ushort_t* bp = Bt + (size_t)colA * KTOT + kglob;
      short8 b0 = *(const short8*)bp;
      short8 b1 = *(const short8*)(bp + 16 * KTOT);
      acc0 = __builtin_amdgcn_mfma_f32_16x16x32_bf16(av.s, b0, acc0, 0, 0, 0);
      acc1 = __builtin_amdgcn_mfma_f32_16x16x32_bf16(av.s, b1, acc1, 0, 0, 0);
    }
    __syncthreads();   // before next group reuses agg
  }

  // -------- root block: A = xh rows of this tile, K = 2048..2175 --------
#pragma unroll
  for (int kk = 0; kk < 4; ++kk) {
    int ko = kk * 32 + q * 8;
    short8 a = *(const short8*)(xh + (size_t)(tile * 16 + m16) * HID + ko);
    const ushort_t* bp = Bt + (size_t)(wave * 32 + m16) * KTOT + 2048 + ko;
    short8 b0 = *(const short8*)bp;
    short8 b1 = *(const short8*)(bp + 16 * KTOT);
    acc0 = __builtin_amdgcn_mfma_f32_16x16x32_bf16(a, b0, acc0, 0, 0, 0);
    acc1 = __builtin_amdgcn_mfma_f32_16x16x32_bf16(a, b1, acc1, 0, 0, 0);
  }

  // -------- epilogue: bias (+relu+bf16 or f32) store. C/D: col=lane&15, row=q*4+reg
  float b0v = bias[wave * 32 + m16];
  float b1v = bias[wave * 32 + 16 + m16];
  int nodeb = tile * 16 + q * 4;
  if (write_f32) {
#pragma unroll
    for (int rg = 0; rg < 4; ++rg) {
      int row = nodeb + rg;
      fout[(size_t)row * HID + wave * 32 + m16]      = acc0[rg] + b0v;
      fout[(size_t)row * HID + wave * 32 + 16 + m16] = acc1[rg] + b1v;
    }
  } else {
#pragma unroll
    for (int rg = 0; rg < 4; ++rg) {
      int row = nodeb + rg;
      float v0 = fmaxf(acc0[rg] + b0v, 0.f);
      float v1 = fmaxf(acc1[rg] + b1v, 0.f);
      union { __hip_bfloat16 h; ushort_t u; } c0, c1;
      c0.h = __float2bfloat16(v0);
      c1.h = __float2bfloat16(v1);
      xh_out[(size_t)row * HID + wave * 32 + m16]      = c0.u;
      xh_out[(size_t)row * HID + wave * 32 + 16 + m16] = c1.u;
    }
  }
}

// ---------------- host ----------------

extern "C" void kernel_launch(void* const* d_in, const int* in_sizes, int n_in,
                              void* d_out, int out_size, void* d_ws, size_t ws_size,
                              hipStream_t stream) {
  const int*   ei        = (const int*)d_in[0];     // (2, E) int32
  const int*   et        = (const int*)d_in[1];     // (E,)   int32
  const float* node_init = (const float*)d_in[2];   // (N, H) f32
  const float* W         = (const float*)d_in[3];   // (3, 16, H, H) f32
  const float* root      = (const float*)d_in[4];   // (3, H, H) f32
  const float* bias      = (const float*)d_in[5];   // (3, H) f32
  float* outp = (float*)d_out;

  // workspace carving (256-B aligned)
  char* ws = (char*)d_ws;
  size_t o = 0;
  auto carve = [&](size_t bytes) { char* p = ws + o; o = (o + bytes + 255) & ~(size_t)255; return p; };
  ushort_t* xh_a    = (ushort_t*)carve((size_t)N_NODES * HID * 2);        // 12.8 MB
  ushort_t* xh_b    = (ushort_t*)carve((size_t)N_NODES * HID * 2);        // 12.8 MB
  int*      payload = (int*)     carve((size_t)N_EDGES * 4);              // 6.4 MB
  int*      off     = (int*)     carve((size_t)(N_BINS + 1) * 4);         // 3.2 MB (hist -> offsets in place)
  int*      cursors = (int*)     carve((size_t)N_BINS * 4);               // 3.2 MB
  int*      totals  = (int*)     carve((size_t)N_SCANBLK * 4);
  ushort_t* Bt      = (ushort_t*)carve((size_t)3 * HID * KTOT * 2);       // 1.67 MB
  (void)ws_size; (void)n_in; (void)in_sizes; (void)out_size;

  // ---- once-per-launch setup: counting sort by (tile, rel, node_local) + Bt ----
  hipLaunchKernelGGL(k_zero,        dim3(N_BINS / 256), dim3(256), 0, stream, off, N_BINS);
  hipLaunchKernelGGL(k_hist,        dim3(N_EDGES / 256), dim3(256), 0, stream, ei, et, off);
  hipLaunchKernelGGL(k_btot,        dim3(N_SCANBLK), dim3(256), 0, stream, off, totals);
  hipLaunchKernelGGL(k_scan_totals, dim3(1), dim3(1024), 0, stream, totals, off);
  hipLaunchKernelGGL(k_scan_within, dim3(N_SCANBLK), dim3(1024), 0, stream, off, totals, cursors);
  hipLaunchKernelGGL(k_sort,        dim3(N_EDGES / 256), dim3(256), 0, stream, ei, et, cursors, payload);
  hipLaunchKernelGGL(k_bt,          dim3(3 * HID * KTOT / 256), dim3(256), 0, stream, W, root, Bt);

  // layer-0 input -> bf16
  hipLaunchKernelGGL(k_xh, dim3(N_NODES * HID / 4 / 256), dim3(256), 0, stream,
                     node_init, xh_a);

  // ---- 3 layers, bf16 ping-pong; relu fused into epilogue of layers 0,1 ----
  // L0: xh_a -> xh_b (bf16+relu); L1: xh_b -> xh_a (bf16+relu); L2: xh_a -> d_out (f32)
  hipLaunchKernelGGL(k_main, dim3(N_TILES), dim3(256), 0, stream,
                     xh_a, xh_b, (float*)nullptr,
                     Bt + (size_t)0 * HID * KTOT, bias + 0 * HID, off, payload, 0);
  hipLaunchKernelGGL(k_main, dim3(N_TILES), dim3(256), 0, stream,
                     xh_b, xh_a, (float*)nullptr,
                     Bt + (size_t)1 * HID * KTOT, bias + 1 * HID, off, payload, 0);
  hipLaunchKernelGGL(k_main, dim3(N_TILES), dim3(256), 0, stream,
                     xh_a, (ushort_t*)nullptr, outp,
                     Bt + (size_t)2 * HID * KTOT, bias + 2 * HID, off, payload, 1);
}

// Round 3
// 1076.321 us; speedup vs baseline: 4.2171x; 4.2171x over previous
//
#include <hip/hip_runtime.h>
#include <hip/hip_bf16.h>

#define N_NODES   50000
#define N_REL     16
#define HID       128
#define N_EDGES   1600000
#define N_TILES   3125          // N_NODES/16
#define N_BINS    800000        // N_TILES*256
#define KTOT      2176          // 17*128 (16 relations + root)
#define N_SCANBLK 782           // ceil(N_BINS/1024)

typedef unsigned short ushort_t;
typedef __attribute__((ext_vector_type(8))) short short8;
typedef __attribute__((ext_vector_type(4))) float f32x4;

union BF2U { __hip_bfloat162 h; unsigned u; };

__device__ __forceinline__ unsigned pack_bf16_2(float x, float y) {
  BF2U c; c.h = __float22bfloat162_rn(make_float2(x, y));
  return c.u;
}

// ---------------- setup kernels ----------------

__global__ __launch_bounds__(256) void k_zero(int* p, int n) {
  int i = blockIdx.x * 256 + threadIdx.x;
  if (i < n) p[i] = 0;
}

__global__ __launch_bounds__(256) void k_hist(const int* __restrict__ ei,
                                              const int* __restrict__ et,
                                              int* __restrict__ hist) {
  int e = blockIdx.x * 256 + threadIdx.x;   // grid covers E exactly
  int tgt = ei[N_EDGES + e];
  int r   = et[e];
  int key = ((tgt >> 4) << 8) | (r << 4) | (tgt & 15);
  atomicAdd(&hist[key], 1);
}

__global__ __launch_bounds__(256) void k_btot(const int* __restrict__ hist,
                                              int* __restrict__ totals) {
  __shared__ int s[256];
  int t = threadIdx.x, b = blockIdx.x;
  int sum = 0;
  for (int j = 0; j < 4; ++j) {
    int idx = b * 1024 + j * 256 + t;
    sum += (idx < N_BINS) ? hist[idx] : 0;
  }
  s[t] = sum; __syncthreads();
  for (int ofs = 128; ofs > 0; ofs >>= 1) {
    if (t < ofs) s[t] += s[t + ofs];
    __syncthreads();
  }
  if (t == 0) totals[b] = s[0];
}

__global__ __launch_bounds__(1024) void k_scan_totals(int* totals, int* off) {
  __shared__ int s[1024];
  int t = threadIdx.x;
  int v = (t < N_SCANBLK) ? totals[t] : 0;
  s[t] = v; __syncthreads();
  for (int ofs = 1; ofs < 1024; ofs <<= 1) {
    int x = (t >= ofs) ? s[t - ofs] : 0;
    __syncthreads();
    s[t] += x;
    __syncthreads();
  }
  if (t < N_SCANBLK) totals[t] = s[t] - v;   // exclusive scan of block totals
  if (t == 0) off[N_BINS] = N_EDGES;
}

__global__ __launch_bounds__(1024) void k_scan_within(int* __restrict__ hist /* becomes off in place */,
                                                      const int* __restrict__ totals,
                                                      int* __restrict__ cursors) {
  __shared__ int s[1024];
  int t = threadIdx.x, blk = blockIdx.x;
  int b = blk * 1024 + t;
  int v = (b < N_BINS) ? hist[b] : 0;
  s[t] = v; __syncthreads();
  for (int ofs = 1; ofs < 1024; ofs <<= 1) {
    int x = (t >= ofs) ? s[t - ofs] : 0;
    __syncthreads();
    s[t] += x;
    __syncthreads();
  }
  if (b < N_BINS) {
    int e = totals[blk] + s[t] - v;
    hist[b] = e;        // exclusive global offset
    cursors[b] = e;
  }
}

__global__ __launch_bounds__(256) void k_sort(const int* __restrict__ ei,
                                              const int* __restrict__ et,
                                              int* __restrict__ cursors,
                                              int* __restrict__ payload) {
  int e = blockIdx.x * 256 + threadIdx.x;
  int src = ei[e];
  int tgt = ei[N_EDGES + e];
  int r   = et[e];
  int key = ((tgt >> 4) << 8) | (r << 4) | (tgt & 15);
  int pos = atomicAdd(&cursors[key], 1);
  payload[pos] = (src << 4) | (tgt & 15);
}

// Bt[l][o][k] = bf16 of (k<2048 ? W[l][k>>7][k&127][o] : root[l][k-2048][o])
__global__ __launch_bounds__(256) void k_bt(const float* __restrict__ W,
                                            const float* __restrict__ root,
                                            ushort_t* __restrict__ Bt) {
  int idx = blockIdx.x * 256 + threadIdx.x;    // 3*128*2176 exact
  int l   = idx / (HID * KTOT);
  int rem = idx - l * HID * KTOT;
  int o   = rem / KTOT;
  int k   = rem - o * KTOT;
  float v;
  if (k < 2048) {
    int r = k >> 7, d = k & 127;
    v = W[((l * N_REL + r) * HID + d) * HID + o];
  } else {
    int d = k - 2048;
    v = root[(l * HID + d) * HID + o];
  }
  __hip_bfloat16 h = __float2bfloat16(v);
  union { __hip_bfloat16 h; ushort_t u; } c; c.h = h;
  Bt[idx] = c.u;
}

// xh = bf16(x)  (layer-0 input conversion only; relu fused in k_main epilogue)
__global__ __launch_bounds__(256) void k_xh(const float* __restrict__ xin,
                                            ushort_t* __restrict__ xh) {
  int i = blockIdx.x * 256 + threadIdx.x;      // grid = N*H/4 exact
  float4 v = ((const float4*)xin)[i];
  uint2 u;
  u.x = pack_bf16_2(v.x, v.y);
  u.y = pack_bf16_2(v.z, v.w);
  ((uint2*)xh)[i] = u;
}

// ---------------- fused per-layer kernel ----------------
// Block: 16-node tile, 4 waves. Each wave owns 32 output cols (2 C-frags).
// 4 relation-groups: wave w gathers relation g*4+w (a contiguous, m-sorted
// edge run). NO LDS atomics: accumulate each bin in 2 registers/lane and
// flush with one plain ds_write_b64 when the (wave-uniform) m changes.
// The bin count falls out of the walk -> scale at flush (no scl/off reads).
// Root (x @ root) is a 17th K-block read directly from global xh.
// Epilogue: layers 0,1 -> bf16(relu(acc+bias)) into xh_out; layer 2 -> f32 out.

__global__ __launch_bounds__(256) void k_main(const ushort_t* __restrict__ xh,
                                              ushort_t* __restrict__ xh_out,
                                              float* __restrict__ fout,
                                              const ushort_t* __restrict__ Bt,
                                              const float* __restrict__ bias,
                                              const int* __restrict__ off,
                                              const int* __restrict__ payload,
                                              int write_f32) {
  __shared__ float agg[4][16][132];   // +4 f32 pad

  const int tile = blockIdx.x;
  const int tid  = threadIdx.x;
  const int wave = tid >> 6;
  const int lane = tid & 63;
  const int m16  = lane & 15;
  const int q    = lane >> 4;

  f32x4 acc0 = {0.f, 0.f, 0.f, 0.f};
  f32x4 acc1 = {0.f, 0.f, 0.f, 0.f};

  const unsigned* xh32 = (const unsigned*)xh;

  for (int g = 0; g < 4; ++g) {
    // zero this wave's agg block (128 cols; pad never read)
    {
      float4 z = {0.f, 0.f, 0.f, 0.f};
      for (int i = lane; i < 512; i += 64) {
        int m = i >> 5, c = (i & 31) << 2;
        *(float4*)&agg[wave][m][c] = z;
      }
    }
    __syncthreads();

    // -------- gather: wave handles relation g*4+wave (contiguous, m-sorted run)
    {
      int base = tile * 256 + (g * 4 + wave) * 16;
      int e0 = off[base];
      int e1 = off[base + 16];

      int   mcur = -1, ecnt = 0;
      float a0 = 0.f, a1 = 0.f;

#define FLUSH()                                                              \
      if (mcur >= 0) {                                                       \
        float s = 1.0f / (float)ecnt;                                        \
        *(float2*)&agg[wave][mcur][lane * 2] = make_float2(a0 * s, a1 * s);  \
      }

#define CONSUME(SP, X)                                                       \
      {                                                                      \
        int mk = (SP) & 15;                                                  \
        if (mk != mcur) { FLUSH(); mcur = mk; a0 = 0.f; a1 = 0.f; ecnt = 0; }\
        a0 += __uint_as_float((X) << 16);                                    \
        a1 += __uint_as_float((X) & 0xffff0000u);                            \
        ecnt++;                                                              \
      }

      for (int c0 = e0; c0 < e1; c0 += 64) {
        int rem = e1 - c0;
        int nb  = rem < 64 ? rem : 64;
        int pv  = payload[c0 + (lane < nb ? lane : nb - 1)];
        int j = 0;
        // full 16-edge batches: payloads -> SGPRs, 16 independent gathers
        for (; j + 16 <= nb; j += 16) {
          int sp[16]; unsigned x[16];
#pragma unroll
          for (int k = 0; k < 16; ++k)
            sp[k] = __builtin_amdgcn_readlane(pv, j + k);
#pragma unroll
          for (int k = 0; k < 16; ++k)
            x[k] = xh32[(sp[k] >> 4) * 64 + lane];
#pragma unroll
          for (int k = 0; k < 16; ++k)
            CONSUME(sp[k], x[k]);
        }
        // tail (<16)
        if (j < nb) {
          int kn = nb - j;
          int sp[16]; unsigned x[16];
#pragma unroll
          for (int k = 0; k < 16; ++k)
            if (k < kn) sp[k] = __builtin_amdgcn_readlane(pv, j + k);
#pragma unroll
          for (int k = 0; k < 16; ++k)
            if (k < kn) x[k] = xh32[(sp[k] >> 4) * 64 + lane];
#pragma unroll
          for (int k = 0; k < 16; ++k)
            if (k < kn) CONSUME(sp[k], x[k]);
        }
      }
      FLUSH();
#undef CONSUME
#undef FLUSH
    }
    __syncthreads();

    // -------- MFMA this group's K = 4*128 --------
    const int colA = wave * 32 + m16;
#pragma unroll
    for (int kk = 0; kk < 16; ++kk) {
      int rl = kk >> 2;
      int ko = (kk & 3) * 32 + q * 8;
      const float* ap = &agg[rl][m16][ko];
      float4 a0 = *(const float4*)ap;
      float4 a1 = *(const float4*)(ap + 4);
      union { unsigned u[4]; short8 s; } av;
      av.u[0] = pack_bf16_2(a0.x, a0.y);
      av.u[1] = pack_bf16_2(a0.z, a0.w);
      av.u[2] = pack_bf16_2(a1.x, a1.y);
      av.u[3] = pack_bf16_2(a1.z, a1.w);
      int kglob = g * 512 + kk * 32 + q * 8;
      const ushort_t* bp = Bt + (size_t)colA * KTOT + kglob;
      short8 b0 = *(const short8*)bp;
      short8 b1 = *(const short8*)(bp + 16 * KTOT);
      acc0 = __builtin_amdgcn_mfma_f32_16x16x32_bf16(av.s, b0, acc0, 0, 0, 0);
      acc1 = __builtin_amdgcn_mfma_f32_16x16x32_bf16(av.s, b1, acc1, 0, 0, 0);
    }
    __syncthreads();   // before next group reuses agg
  }

  // -------- root block: A = xh rows of this tile, K = 2048..2175 --------
#pragma unroll
  for (int kk = 0; kk < 4; ++kk) {
    int ko = kk * 32 + q * 8;
    short8 a = *(const short8*)(xh + (size_t)(tile * 16 + m16) * HID + ko);
    const ushort_t* bp = Bt + (size_t)(wave * 32 + m16) * KTOT + 2048 + ko;
    short8 b0 = *(const short8*)bp;
    short8 b1 = *(const short8*)(bp + 16 * KTOT);
    acc0 = __builtin_amdgcn_mfma_f32_16x16x32_bf16(a, b0, acc0, 0, 0, 0);
    acc1 = __builtin_amdgcn_mfma_f32_16x16x32_bf16(a, b1, acc1, 0, 0, 0);
  }

  // -------- epilogue: bias (+relu+bf16 or f32) store. C/D: col=lane&15, row=q*4+reg
  float b0v = bias[wave * 32 + m16];
  float b1v = bias[wave * 32 + 16 + m16];
  int nodeb = tile * 16 + q * 4;
  if (write_f32) {
#pragma unroll
    for (int rg = 0; rg < 4; ++rg) {
      int row = nodeb + rg;
      fout[(size_t)row * HID + wave * 32 + m16]      = acc0[rg] + b0v;
      fout[(size_t)row * HID + wave * 32 + 16 + m16] = acc1[rg] + b1v;
    }
  } else {
#pragma unroll
    for (int rg = 0; rg < 4; ++rg) {
      int row = nodeb + rg;
      float v0 = fmaxf(acc0[rg] + b0v, 0.f);
      float v1 = fmaxf(acc1[rg] + b1v, 0.f);
      union { __hip_bfloat16 h; ushort_t u; } c0, c1;
      c0.h = __float2bfloat16(v0);
      c1.h = __float2bfloat16(v1);
      xh_out[(size_t)row * HID + wave * 32 + m16]      = c0.u;
      xh_out[(size_t)row * HID + wave * 32 + 16 + m16] = c1.u;
    }
  }
}

// ---------------- host ----------------

extern "C" void kernel_launch(void* const* d_in, const int* in_sizes, int n_in,
                              void* d_out, int out_size, void* d_ws, size_t ws_size,
                              hipStream_t stream) {
  const int*   ei        = (const int*)d_in[0];     // (2, E) int32
  const int*   et        = (const int*)d_in[1];     // (E,)   int32
  const float* node_init = (const float*)d_in[2];   // (N, H) f32
  const float* W         = (const float*)d_in[3];   // (3, 16, H, H) f32
  const float* root      = (const float*)d_in[4];   // (3, H, H) f32
  const float* bias      = (const float*)d_in[5];   // (3, H) f32
  float* outp = (float*)d_out;

  // workspace carving (256-B aligned)
  char* ws = (char*)d_ws;
  size_t o = 0;
  auto carve = [&](size_t bytes) { char* p = ws + o; o = (o + bytes + 255) & ~(size_t)255; return p; };
  ushort_t* xh_a    = (ushort_t*)carve((size_t)N_NODES * HID * 2);        // 12.8 MB
  ushort_t* xh_b    = (ushort_t*)carve((size_t)N_NODES * HID * 2);        // 12.8 MB
  int*      payload = (int*)     carve((size_t)N_EDGES * 4);              // 6.4 MB
  int*      off     = (int*)     carve((size_t)(N_BINS + 1) * 4);         // 3.2 MB (hist -> offsets in place)
  int*      cursors = (int*)     carve((size_t)N_BINS * 4);               // 3.2 MB
  int*      totals  = (int*)     carve((size_t)N_SCANBLK * 4);
  ushort_t* Bt      = (ushort_t*)carve((size_t)3 * HID * KTOT * 2);       // 1.67 MB
  (void)ws_size; (void)n_in; (void)in_sizes; (void)out_size;

  // ---- once-per-launch setup: counting sort by (tile, rel, node_local) + Bt ----
  hipLaunchKernelGGL(k_zero,        dim3(N_BINS / 256), dim3(256), 0, stream, off, N_BINS);
  hipLaunchKernelGGL(k_hist,        dim3(N_EDGES / 256), dim3(256), 0, stream, ei, et, off);
  hipLaunchKernelGGL(k_btot,        dim3(N_SCANBLK), dim3(256), 0, stream, off, totals);
  hipLaunchKernelGGL(k_scan_totals, dim3(1), dim3(1024), 0, stream, totals, off);
  hipLaunchKernelGGL(k_scan_within, dim3(N_SCANBLK), dim3(1024), 0, stream, off, totals, cursors);
  hipLaunchKernelGGL(k_sort,        dim3(N_EDGES / 256), dim3(256), 0, stream, ei, et, cursors, payload);
  hipLaunchKernelGGL(k_bt,          dim3(3 * HID * KTOT / 256), dim3(256), 0, stream, W, root, Bt);

  // layer-0 input -> bf16
  hipLaunchKernelGGL(k_xh, dim3(N_NODES * HID / 4 / 256), dim3(256), 0, stream,
                     node_init, xh_a);

  // ---- 3 layers, bf16 ping-pong; relu fused into epilogue of layers 0,1 ----
  // L0: xh_a -> xh_b (bf16+relu); L1: xh_b -> xh_a (bf16+relu); L2: xh_a -> d_out (f32)
  hipLaunchKernelGGL(k_main, dim3(N_TILES), dim3(256), 0, stream,
                     xh_a, xh_b, (float*)nullptr,
                     Bt + (size_t)0 * HID * KTOT, bias + 0 * HID, off, payload, 0);
  hipLaunchKernelGGL(k_main, dim3(N_TILES), dim3(256), 0, stream,
                     xh_b, xh_a, (float*)nullptr,
                     Bt + (size_t)1 * HID * KTOT, bias + 1 * HID, off, payload, 0);
  hipLaunchKernelGGL(k_main, dim3(N_TILES), dim3(256), 0, stream,
                     xh_a, (ushort_t*)nullptr, outp,
                     Bt + (size_t)2 * HID * KTOT, bias + 2 * HID, off, payload, 1);
}